// Round 12
// baseline (22.033 us; speedup 1.0000x reference)
//
#include <hip/hip_runtime.h>

namespace {
constexpr int kB   = 2;
constexpr int kC   = 64;
constexpr int kH   = 128;
constexpr int kW   = 240;
constexpr int kD0  = 16;          // disps 0,3,...,45
constexpr int kD1  = 5;           // disps -2,-1,0,1,2
constexpr int kWc1 = 285;
constexpr int kWc2 = 242;
constexpr int kPad = 48;          // left pad (>= max disp 45)
constexpr int kRow = 336;         // dwords per cpair row: 48 pad |240 data |48 pad
constexpr int kRowBytes = kRow * 4;   // 1344
constexpr int kCP  = 32;          // channel pairs (64 channels)
constexpr int kThreads = 320;     // 5 waves; thread owns ONE column, ALL cpairs
constexpr int kOut1 = kB * kD0 * kH * kWc1;
typedef unsigned int v2u __attribute__((ext_vector_type(2)));
typedef float v2f __attribute__((ext_vector_type(2)));

__device__ __forceinline__ v2f UP(unsigned int x) {   // bf16x2 -> {lo,hi} f32
  v2f f;
  f.x = __uint_as_float(x << 16);
  f.y = __uint_as_float(x & 0xffff0000u);
  return f;
}
__device__ __forceinline__ unsigned int pk2(float lo, float hi) {
  unsigned int r;
  asm("v_cvt_pk_bf16_f32 %0, %1, %2" : "=v"(r) : "v"(lo), "v"(hi));
  return r;
}
__device__ __forceinline__ v2f pfma(v2f a, v2f b, v2f c) {
  return __builtin_elementwise_fma(a, b, c);   // -> v_pk_fma_f32
}

// R9's validated per-cpair math (packed f32) on the 10 fetched tap dwords.
__device__ __forceinline__ void process10(
    v2u p0, v2u p1, v2u p2, v2u p3, v2u p4, v2u p5, v2u p6, v2u p7,
    v2u q0, v2u q1, v2f (&acc1)[kD0], v2f (&acc2)[kD1]) {
  const v2f f0  = UP(p0.x), f1  = UP(p0.y), f2  = UP(p1.x), f3  = UP(p1.y);
  const v2f f4  = UP(p2.x), f5  = UP(p2.y), f6  = UP(p3.x), f7  = UP(p3.y);
  const v2f f8  = UP(p4.x), f9  = UP(p4.y), f10 = UP(p5.x), f11 = UP(p5.y);
  const v2f f12 = UP(p6.x), f13 = UP(p6.y), f14 = UP(p7.x), f15 = UP(p7.y);
  const v2f e0 = UP(q0.x), e1 = UP(q0.y);   // tap offsets 43, 44
  const v2f e2 = UP(q1.x), e3 = UP(q1.y);   // tap offsets 46, 47
  const v2f s = (((f0 + f1) + (f2 + f3)) + ((f4 + f5) + (f6 + f7))) +
                (((f8 + f9) + (f10 + f11)) + ((f12 + f13) + (f14 + f15)));
  v2f r;
  r.x = __builtin_amdgcn_rcpf(s.x);
  r.y = __builtin_amdgcn_rcpf(s.y);
  acc1[0]  = pfma(f0,  r, acc1[0]);   acc1[1]  = pfma(f1,  r, acc1[1]);
  acc1[2]  = pfma(f2,  r, acc1[2]);   acc1[3]  = pfma(f3,  r, acc1[3]);
  acc1[4]  = pfma(f4,  r, acc1[4]);   acc1[5]  = pfma(f5,  r, acc1[5]);
  acc1[6]  = pfma(f6,  r, acc1[6]);   acc1[7]  = pfma(f7,  r, acc1[7]);
  acc1[8]  = pfma(f8,  r, acc1[8]);   acc1[9]  = pfma(f9,  r, acc1[9]);
  acc1[10] = pfma(f10, r, acc1[10]);  acc1[11] = pfma(f11, r, acc1[11]);
  acc1[12] = pfma(f12, r, acc1[12]);  acc1[13] = pfma(f13, r, acc1[13]);
  acc1[14] = pfma(f14, r, acc1[14]);  acc1[15] = pfma(f15, r, acc1[15]);
  const v2f s2 = ((e0 + e1) + (e2 + e3)) + f0;
  v2f r2;
  r2.x = __builtin_amdgcn_rcpf(s2.x);
  r2.y = __builtin_amdgcn_rcpf(s2.y);
  acc2[0] = pfma(e3, r2, acc2[0]);
  acc2[1] = pfma(e2, r2, acc2[1]);
  acc2[2] = pfma(f0, r2, acc2[2]);
  acc2[3] = pfma(e1, r2, acc2[3]);
  acc2[4] = pfma(e0, r2, acc2[4]);
}
}  // namespace

__global__ __launch_bounds__(kThreads)
void anynet_disp_kernel(const float* __restrict__ fr, float* __restrict__ out) {
  __shared__ unsigned int E[kCP * kRow];  // 43 KB bf16x2 exp(feat_r)
  const int bh  = blockIdx.x;             // 0..255
  const int b   = bh >> 7;
  const int h   = bh & 127;
  const int tid = threadIdx.x;

  // ---- phase A0: pads = bf16(1.0)x2 (= exp(0), "invalid disparity")
  const uint4 ones = {0x3F803F80u, 0x3F803F80u, 0x3F803F80u, 0x3F803F80u};
  #pragma unroll
  for (int r = 0; r < 3; ++r) {
    const int i = tid + r * kThreads;
    if (i < kCP * 24) {
      const int cp = i / 24, q = i % 24;
      const int j4 = (q < 12) ? q : q + 60;  // uint4 [0,12) and [72,84)
      *reinterpret_cast<uint4*>(&E[cp * kRow + 4 * j4]) = ones;
    }
  }
  // ---- phase A1: stage exp as bf16 cpairs; 1920 items = exactly 6/thread.
  // Issue all 12 global loads first (MLP), then exp+pack+store.
  const float* fr_b = fr + (size_t)b * kC * kH * kW + (size_t)h * kW;
  {
    float4 la[6], lb[6];
    #pragma unroll
    for (int u = 0; u < 6; ++u) {
      const int i  = tid + u * kThreads;    // max 1919 < 1920, no guard
      const int cp = i / 60, xq = i % 60;
      const size_t off = (size_t)(2 * cp) * (kH * kW) + 4 * xq;
      la[u] = *reinterpret_cast<const float4*>(fr_b + off);
      lb[u] = *reinterpret_cast<const float4*>(fr_b + off + (size_t)kH * kW);
    }
    #pragma unroll
    for (int u = 0; u < 6; ++u) {
      const int i  = tid + u * kThreads;
      const int cp = i / 60, xq = i % 60;
      uint4 w;
      w.x = pk2(__expf(la[u].x), __expf(lb[u].x));
      w.y = pk2(__expf(la[u].y), __expf(lb[u].y));
      w.z = pk2(__expf(la[u].z), __expf(lb[u].z));
      w.w = pk2(__expf(la[u].w), __expf(lb[u].w));
      *reinterpret_cast<uint4*>(&E[cp * kRow + kPad + 4 * xq]) = w;
    }
  }
  __syncthreads();   // the ONLY barrier

  // ---- phase B: thread owns column tid; sweeps ALL 32 cpairs. Fused
  // issue+wait asm per row (R7-R9 proven; no cross-block in-flight regs).
  const int col = tid;
  if (col < kWc1) {
    v2f acc1[kD0] = {};
    v2f acc2[kD1] = {};
    unsigned int addr = (unsigned int)(uintptr_t)(const void*)&E[col + 3];
    for (int cc = 0; cc < kCP; ++cc) {
      v2u p0, p1, p2, p3, p4, p5, p6, p7, q0, q1;
      asm volatile(
          "ds_read2_b32 %0, %10 offset0:45 offset1:42\n\t"
          "ds_read2_b32 %1, %10 offset0:39 offset1:36\n\t"
          "ds_read2_b32 %2, %10 offset0:33 offset1:30\n\t"
          "ds_read2_b32 %3, %10 offset0:27 offset1:24\n\t"
          "ds_read2_b32 %4, %10 offset0:21 offset1:18\n\t"
          "ds_read2_b32 %5, %10 offset0:15 offset1:12\n\t"
          "ds_read2_b32 %6, %10 offset0:9 offset1:6\n\t"
          "ds_read2_b32 %7, %10 offset0:3 offset1:0\n\t"
          "ds_read2_b32 %8, %10 offset0:43 offset1:44\n\t"
          "ds_read2_b32 %9, %10 offset0:46 offset1:47\n\t"
          "s_waitcnt lgkmcnt(0)"
          : "=&v"(p0), "=&v"(p1), "=&v"(p2), "=&v"(p3), "=&v"(p4),
            "=&v"(p5), "=&v"(p6), "=&v"(p7), "=&v"(q0), "=&v"(q1)
          : "v"(addr));
      process10(p0, p1, p2, p3, p4, p5, p6, p7, q0, q1, acc1, acc2);
      addr += kRowBytes;
    }

    // ---- direct stores: no LDS round-trip, coalesced across threads
    #pragma unroll
    for (int d = 0; d < kD0; ++d)
      out[((b * kD0 + d) * kH + h) * kWc1 + col] =
          (3.0f * (float)d) * (4.0f + acc1[d].x + acc1[d].y);     // C/D0 = 4
    if (col < kWc2) {
      #pragma unroll
      for (int j = 0; j < kD1; ++j)
        out[kOut1 + ((b * kD1 + j) * kH + h) * kWc2 + col] =
            (float)(j - 2) * (64.0f / 5.0f + acc2[j].x + acc2[j].y);  // C/D1
    }
  }
}

extern "C" void kernel_launch(void* const* d_in, const int* in_sizes, int n_in,
                              void* d_out, int out_size, void* d_ws, size_t ws_size,
                              hipStream_t stream) {
  const float* feat_r = (const float*)d_in[1];  // feats_l contributes exactly C/D
  float* out = (float*)d_out;
  anynet_disp_kernel<<<dim3(kB * kH), dim3(kThreads), 0, stream>>>(feat_r, out);
}